// Round 12
// baseline (16890.814 us; speedup 1.0000x reference)
//
#include <hip/hip_runtime.h>

#define OUTD 66
#define INW  78
#define FH   2048
#define LEN  64

typedef short bf16x8 __attribute__((ext_vector_type(8)));
typedef float f32x4  __attribute__((ext_vector_type(4)));

__device__ __forceinline__ float bf2f(unsigned short u) {
  union { unsigned int i; float f; } v; v.i = ((unsigned int)u) << 16; return v.f;
}
__device__ __forceinline__ unsigned short f2bf(float f) {
  union { float f; unsigned int i; } v; v.f = f;
  unsigned int u = v.i;
  return (unsigned short)((u + 0x7fffu + ((u >> 16) & 1u)) >> 16);
}
__device__ __forceinline__ float sigm(float x) { return 1.f / (1.f + __expf(-x)); }
__device__ __forceinline__ float tanh_f(float x) { return 2.f / (1.f + __expf(-2.f * x)) - 1.f; }

// ---- initA (all inputs FLOAT32):
//  blocks 0..255 : Weff(bf16) = W_hh + W_ihA·W_fc fold, bias_eff(f32), zero flags/flagsL
//  blocks 256..511: h0 -> hbuf[0] (bf16), c0 (f32); block 256 also converts W_fc -> Wfc16
__global__ __launch_bounds__(256) void k_initA(
    const float* __restrict__ W_hh, const float* __restrict__ W_ih,
    const float* __restrict__ W_fc, const float* __restrict__ b_ih,
    const float* __restrict__ b_hh, const float* __restrict__ b_fc,
    const float* __restrict__ inp, const float* __restrict__ W_inh,
    const float* __restrict__ b_inh, const float* __restrict__ W_inc,
    const float* __restrict__ b_inc,
    unsigned short* __restrict__ Weff, float* __restrict__ bias_eff,
    unsigned short* __restrict__ hbuf, float* __restrict__ c0,
    unsigned short* __restrict__ Wfc16, unsigned int* __restrict__ flags,
    unsigned int* __restrict__ flagsL)
{
  int tid = threadIdx.x, bid = blockIdx.x;
  if (bid < 256) {
    int nb = bid;
    int k = tid * 2;
    float acc[8][2];
    #pragma unroll
    for (int r = 0; r < 8; ++r) {
      int n = nb * 8 + r;
      acc[r][0] = W_hh[n * 512 + k];
      acc[r][1] = W_hh[n * 512 + k + 1];
    }
    for (int m = 0; m < OUTD; ++m) {
      float w0 = W_fc[m * 512 + k];
      float w1 = W_fc[m * 512 + k + 1];
      #pragma unroll
      for (int r = 0; r < 8; ++r) {
        float wih = W_ih[(nb * 8 + r) * INW + m];
        acc[r][0] += wih * w0;
        acc[r][1] += wih * w1;
      }
    }
    #pragma unroll
    for (int r = 0; r < 8; ++r) {
      int n = nb * 8 + r;
      unsigned int pack = (unsigned int)f2bf(acc[r][0]) | ((unsigned int)f2bf(acc[r][1]) << 16);
      *(unsigned int*)(Weff + n * 512 + k) = pack;
    }
    if (tid < 8) {
      int n = nb * 8 + tid;
      float a = b_ih[n] + b_hh[n];
      for (int m = 0; m < OUTD; ++m) a += b_fc[m] * W_ih[n * INW + m];
      bias_eff[n] = a;
    }
    if (nb == 0) {
      for (int i = tid; i < 512 * 16; i += 256) flags[i] = 0;
      for (int i = tid; i < 256 * 16; i += 256) flagsL[i] = 0;
    }
  } else {
    int nb = bid - 256;
    for (int r = 0; r < 2; ++r) {
      int b = nb * 2 + r;
      for (int half = 0; half < 2; ++half) {
        int c = tid + half * 256;
        float ha = b_inh[c], ca = b_inc[c];
        for (int m = 0; m < OUTD; ++m) {
          float f = inp[b * OUTD + m];
          ha += f * W_inh[c * OUTD + m];
          ca += f * W_inc[c * OUTD + m];
        }
        hbuf[b * 512 + c] = f2bf(ha);
        c0[b * 512 + c] = ca;
      }
    }
    if (nb == 0) {
      for (int i = tid; i < OUTD * 512; i += 256) Wfc16[i] = f2bf(W_fc[i]);
    }
  }
}

// ---- init2a: d0[b][m] = frame0 - (h0(bf16) @ W_fc^T + b_fc)
__global__ __launch_bounds__(128) void k_init2a(
    const float* __restrict__ inp, const unsigned short* __restrict__ hbuf,
    const float* __restrict__ W_fc, const float* __restrict__ b_fc,
    float* __restrict__ d0)
{
  int b = blockIdx.x, m = threadIdx.x;
  if (m >= OUTD) return;
  const unsigned short* hrow = hbuf + b * 512;
  const float* wrow = W_fc + m * 512;
  float acc = 0.f;
  for (int k = 0; k < 512; ++k) acc += bf2f(hrow[k]) * wrow[k];
  d0[b * OUTD + m] = inp[b * OUTD + m] - (acc + b_fc[m]);
}

// ---- init2b: corr0[b][n] = d0[b] @ W_ihA[n]^T
__global__ __launch_bounds__(256) void k_init2b(
    const float* __restrict__ d0, const float* __restrict__ W_ih,
    float* __restrict__ corr0)
{
  __shared__ float ds[4][OUTD];
  int tid = threadIdx.x, b0 = blockIdx.x * 4;
  for (int i = tid; i < 4 * OUTD; i += 256) ds[i / OUTD][i % OUTD] = d0[b0 * OUTD + i];
  __syncthreads();
  for (int n = tid; n < FH; n += 256) {
    float a0 = 0, a1 = 0, a2 = 0, a3 = 0;
    const float* wr = W_ih + n * INW;
    for (int m = 0; m < OUTD; ++m) {
      float w = wr[m];
      a0 += ds[0][m] * w; a1 += ds[1][m] * w; a2 += ds[2][m] * w; a3 += ds[3][m] * w;
    }
    corr0[(b0 + 0) * FH + n] = a0;
    corr0[(b0 + 1) * FH + n] = a1;
    corr0[(b0 + 2) * FH + n] = a2;
    corr0[(b0 + 3) * FH + n] = a3;
  }
}

// ---- main persistent LSTM kernel (r10 structure: LDS staging, wave0 poll).
// block = 64 batch rows (group mt) x 16 hidden cols (jt). Leader-verified XCD fast
// path (r10). NEW: dual-channel flags — in fast mode producers also publish to an
// XCD-local channel (plain store -> shared local L2) and wave0 polls it with sc0
// (L1-bypass, L2-hit) for a BOUNDED spin count, then falls back to the proven
// agent-scope (L3) channel. Worst case == r10; no hang possible.
__global__ __launch_bounds__(256, 1) void k_main(
    const unsigned short* __restrict__ Weff, const float* __restrict__ bias_eff,
    unsigned short* __restrict__ hbuf, const float* __restrict__ c0,
    const float* __restrict__ corr0, const float* __restrict__ W_ih,
    const int* __restrict__ labels, const unsigned short* __restrict__ Wfc16,
    const float* __restrict__ b_fc, float* __restrict__ out,
    unsigned int* __restrict__ flags, unsigned int* __restrict__ flagsL)
{
  __shared__ __align__(16) unsigned short h_lds[64 * 512];  // 65536 B, XOR-swizzled 16B granules

  int tid = threadIdx.x, bid = blockIdx.x;
  int w = tid >> 6, lane = tid & 63;
  int lc = lane & 15, kg = lane >> 4;
  unsigned int* xmap = flags + 4096;          // [256] stride-16 XCD map
  unsigned int* decp = flags + 4088;          // decision word

  // ---- publish my XCC_ID (gfx950-verified: learn_hip m09)
  unsigned int xcd;
  asm volatile("s_getreg_b32 %0, hwreg(HW_REG_XCC_ID)" : "=s"(xcd));
  if (tid == 0)
    __hip_atomic_store(&xmap[bid * 16], xcd + 1u, __ATOMIC_RELAXED, __HIP_MEMORY_SCOPE_AGENT);

  // ---- leader (block 0, wave 0) verifies both candidate layouts, publishes decision
  if (bid == 0 && w == 0) {
    int okA = 1, okB = 1;
    #pragma unroll
    for (int i = 0; i < 4; ++i) {
      int b = lane + i * 64;
      unsigned int v, ra, rb;
      const unsigned int* xp = &xmap[b * 16];
      for (;;) { v = __hip_atomic_load(xp, __ATOMIC_RELAXED, __HIP_MEMORY_SCOPE_AGENT);
                 if (v) break; __builtin_amdgcn_s_sleep(1); }
      const unsigned int* pa = &xmap[(b & 7) * 16];
      for (;;) { ra = __hip_atomic_load(pa, __ATOMIC_RELAXED, __HIP_MEMORY_SCOPE_AGENT);
                 if (ra) break; __builtin_amdgcn_s_sleep(1); }
      const unsigned int* pb = &xmap[((b >> 5) << 5) * 16];
      for (;;) { rb = __hip_atomic_load(pb, __ATOMIC_RELAXED, __HIP_MEMORY_SCOPE_AGENT);
                 if (rb) break; __builtin_amdgcn_s_sleep(1); }
      okA &= (v == ra); okB &= (v == rb);
    }
    okA = __all(okA); okB = __all(okB);
    if (lane == 0) {
      unsigned int d = okA ? 1u : (okB ? 2u : 3u);
      __hip_atomic_store(decp, d, __ATOMIC_RELAXED, __HIP_MEMORY_SCOPE_AGENT);
    }
  }
  if (tid == 0) {
    unsigned int dd;
    for (;;) { dd = __hip_atomic_load(decp, __ATOMIC_RELAXED, __HIP_MEMORY_SCOPE_AGENT);
               if (dd) break; __builtin_amdgcn_s_sleep(1); }
    h_lds[0] = (unsigned short)dd;
  }
  __syncthreads();
  unsigned int dmode = h_lds[0];
  __syncthreads();

  int fast, mt, jt;
  if (dmode == 1u)      { fast = 1; mt = bid & 7;  jt = bid >> 3; }
  else if (dmode == 2u) { fast = 1; mt = bid >> 5; jt = bid & 31; }
  else                  { fast = 0; mt = bid & 7;  jt = bid >> 3; }

  int row0 = mt * 64, j0 = jt * 16;
  int hx0 = (w >> 1) * 8;
  int xloc = lc & 7;
  int G = lc >> 3;                       // 0: holds gates i,g ; 1: holds f,o
  int hcol = j0 + hx0 + xloc;            // global hidden col this lane activates
  int rw0 = (w & 1) * 32;                // wave-local row base

  // LDS swizzle precompute (addr_i = P ^ (i<<6))
  int sA = xloc;
  int tA16 = ((kg ^ sA) & 3) << 4;
  int ue64 = ((sA >> 2) & 1) << 6;
  int PA0 = (rw0 + lc) * 1024 + tA16 + ue64;
  int PA1 = PA0 + 16 * 1024;
  int PF  = (w * 16 + lc) * 1024 + tA16 + ue64;

  // ---- Weff B fragments (step-invariant)
  bf16x8 Bfrag[16][2];
  #pragma unroll
  for (int cg = 0; cg < 2; ++cg) {
    int n = (cg * 2 + G) * 512 + hcol;
    const unsigned short* p = Weff + n * 512 + kg * 8;
    #pragma unroll
    for (int i = 0; i < 16; ++i) Bfrag[i][cg] = *(const bf16x8*)(p + i * 32);
  }

  // ---- W_fc B fragments for fused fc (jt<5 covers out cols 0..79, guard <66)
  bf16x8 Wf[16];
  float fcb = 0.f;
  {
    int n = j0 + lc;
    if (jt < 5 && n < OUTD) {
      const unsigned short* p = Wfc16 + n * 512 + kg * 8;
      #pragma unroll
      for (int i = 0; i < 16; ++i) Wf[i] = *(const bf16x8*)(p + i * 32);
      fcb = b_fc[n];
    } else {
      bf16x8 z8 = {0, 0, 0, 0, 0, 0, 0, 0};
      #pragma unroll
      for (int i = 0; i < 16; ++i) Wf[i] = z8;
    }
  }

  // ---- activation constants
  int qsel = G * 2;
  float lt[4][4], creg[4];
  #pragma unroll
  for (int idx = 0; idx < 4; ++idx) {
    int rloc = rw0 + (idx >> 1) * 16 + kg * 4 + qsel + (idx & 1);
    int grow = row0 + rloc;
    int lab = labels[grow];
    #pragma unroll
    for (int gt = 0; gt < 4; ++gt) {
      int n = gt * 512 + hcol;
      lt[gt][idx] = bias_eff[n] + W_ih[n * INW + OUTD + lab];
    }
    creg[idx] = c0[grow * 512 + hcol];
  }

  const f32x4 z = {0.f, 0.f, 0.f, 0.f};
  unsigned int* myflag  = &flags[(mt * 32 + jt) * 16];
  unsigned int* myflagL = &flagsL[(mt * 32 + jt) * 16];
  const unsigned int* fpoll  = flags  + (mt * 32 + (lane & 31)) * 16;
  const unsigned int* fpollL = flagsL + (mt * 32 + (lane & 31)) * 16;

  for (int s = 0; s < LEN; ++s) {
    // stage h_s (parity s&1) -> swizzled LDS
    const unsigned short* hsrc = hbuf + (s & 1) * 262144 + row0 * 512;
    #pragma unroll
    for (int i = 0; i < 16; ++i) {
      int chunk = tid + i * 256;
      int r = chunk >> 6, g = chunk & 63;
      int dst = r * 512 + ((g ^ (r & 7)) << 3);
      *(uint4*)(h_lds + dst) = *(const uint4*)(hsrc + r * 512 + g * 8);
    }
    __syncthreads();

    // gates = h_s @ Weff
    f32x4 acc00 = z, acc01 = z, acc10 = z, acc11 = z;
    #pragma unroll
    for (int i = 0; i < 16; ++i) {
      bf16x8 a0 = *(const bf16x8*)((const char*)h_lds + (PA0 ^ (i << 6)));
      bf16x8 a1 = *(const bf16x8*)((const char*)h_lds + (PA1 ^ (i << 6)));
      acc00 = __builtin_amdgcn_mfma_f32_16x16x32_bf16(a0, Bfrag[i][0], acc00, 0, 0, 0);
      acc10 = __builtin_amdgcn_mfma_f32_16x16x32_bf16(a1, Bfrag[i][0], acc10, 0, 0, 0);
      acc01 = __builtin_amdgcn_mfma_f32_16x16x32_bf16(a0, Bfrag[i][1], acc01, 0, 0, 0);
      acc11 = __builtin_amdgcn_mfma_f32_16x16x32_bf16(a1, Bfrag[i][1], acc11, 0, 0, 0);
    }

    // exchange missing gates with partner lane (lane^8)
    f32x4 sh00, sh01, sh10, sh11;
    #pragma unroll
    for (int j = 0; j < 4; ++j) {
      sh00[j] = __shfl_xor(acc00[j], 8);
      sh01[j] = __shfl_xor(acc01[j], 8);
      sh10[j] = __shfl_xor(acc10[j], 8);
      sh11[j] = __shfl_xor(acc11[j], 8);
    }

    // activation
    unsigned short hval[4];
    #pragma unroll
    for (int idx = 0; idx < 4; ++idx) {
      int jj = idx & 1, hh = idx >> 1;
      int qo = qsel + jj;
      float xi, xf, xg, xo;
      if (hh == 0) {
        xi = (G ? sh00[qo] : acc00[qo]);
        xf = (G ? acc00[qo] : sh00[qo]);
        xg = (G ? sh01[qo] : acc01[qo]);
        xo = (G ? acc01[qo] : sh01[qo]);
      } else {
        xi = (G ? sh10[qo] : acc10[qo]);
        xf = (G ? acc10[qo] : sh10[qo]);
        xg = (G ? sh11[qo] : acc11[qo]);
        xo = (G ? acc11[qo] : sh11[qo]);
      }
      xi += lt[0][idx]; xf += lt[1][idx]; xg += lt[2][idx]; xo += lt[3][idx];
      if (s == 0) {
        int rloc = rw0 + hh * 16 + kg * 4 + qo;
        const float* cr = corr0 + (long)(row0 + rloc) * FH + hcol;
        xi += cr[0]; xf += cr[512]; xg += cr[1024]; xo += cr[1536];
      }
      float cn = sigm(xf) * creg[idx] + sigm(xi) * tanh_f(xg);
      creg[idx] = cn;
      hval[idx] = f2bf(sigm(xo) * tanh_f(cn));
    }

    // ---- store h_{s+1} (opposite parity); pack lane pairs into u32.
    {
      unsigned int* hdst32 = (unsigned int*)(hbuf + ((s + 1) & 1) * 262144);
      int ce = (hcol & ~1) >> 1;
      int odd = xloc & 1;
      unsigned int pk[2]; int ro[2]; int np = 0;
      #pragma unroll
      for (int idx = 0; idx < 4; ++idx) {
        unsigned int mine = hval[idx];
        unsigned int part = (unsigned int)__shfl_xor((int)mine, 1);
        unsigned int p = odd ? (part | (mine << 16)) : (mine | (part << 16));
        if ((idx >> 1) == odd) {
          int rloc = rw0 + (idx >> 1) * 16 + kg * 4 + qsel + (idx & 1);
          pk[np] = p; ro[np] = (row0 + rloc) * 256 + ce; ++np;
        }
      }
      if (fast) {
        hdst32[ro[0]] = pk[0];
        hdst32[ro[1]] = pk[1];
      } else {
        __hip_atomic_store(&hdst32[ro[0]], pk[0], __ATOMIC_RELAXED, __HIP_MEMORY_SCOPE_AGENT);
        __hip_atomic_store(&hdst32[ro[1]], pk[1], __ATOMIC_RELAXED, __HIP_MEMORY_SCOPE_AGENT);
      }
    }

    // ---- producer flags: drain all h stores, then tid0 dual-publishes step.
    __builtin_amdgcn_s_waitcnt(0);
    __syncthreads();
    if (tid == 0) {
      if (fast) *myflagL = (unsigned int)(s + 1);          // local L2 channel
      __hip_atomic_store(myflag, (unsigned int)(s + 1),    // L3 channel (always)
                         __ATOMIC_RELAXED, __HIP_MEMORY_SCOPE_AGENT);
    }

    // fused fc in the wait window: out[:, s-1, :] = h_s @ W_fc^T + b_fc
    if (jt < 5 && s >= 1) {
      f32x4 fa = z;
      #pragma unroll
      for (int i = 0; i < 16; ++i) {
        bf16x8 a = *(const bf16x8*)((const char*)h_lds + (PF ^ (i << 6)));
        fa = __builtin_amdgcn_mfma_f32_16x16x32_bf16(a, Wf[i], fa, 0, 0, 0);
      }
      int c = j0 + lc;
      if (c < OUTD) {
        #pragma unroll
        for (int q = 0; q < 4; ++q) {
          int b = row0 + w * 16 + kg * 4 + q;
          out[((long)b * 64 + (s - 1)) * OUTD + c] = fa[q] + fcb;
        }
      }
    }

    // ---- consumer wait (wave0): bounded sc0 poll of local channel, fallback to L3.
    if (w == 0) {
      int done = 0;
      if (fast) {
        for (int t = 0; t < 3000; ++t) {
          unsigned int v;
          asm volatile("global_load_dword %0, %1, off sc0\n\ts_waitcnt vmcnt(0)"
                       : "=v"(v) : "v"(fpollL) : "memory");
          if (__all((int)(v >= (unsigned int)(s + 1)))) { done = 1; break; }
        }
      }
      if (!done) {
        for (;;) {
          unsigned int v = __hip_atomic_load(fpoll, __ATOMIC_RELAXED, __HIP_MEMORY_SCOPE_AGENT);
          if (__all((int)(v >= (unsigned int)(s + 1)))) break;
          __builtin_amdgcn_s_sleep(1);
        }
      }
      __builtin_amdgcn_fence(__ATOMIC_ACQUIRE, "agent");   // L1 inv (cheap, measured)
    }
    __syncthreads();
  }

  // epilogue: out[:, 63, :] = h_64 @ W_fc^T + b_fc   (h_64 at parity 0)
  if (jt < 5) {
    const unsigned short* hsrc = hbuf + row0 * 512;
    #pragma unroll
    for (int i = 0; i < 16; ++i) {
      int chunk = tid + i * 256;
      int r = chunk >> 6, g = chunk & 63;
      int dst = r * 512 + ((g ^ (r & 7)) << 3);
      *(uint4*)(h_lds + dst) = *(const uint4*)(hsrc + r * 512 + g * 8);
    }
    __syncthreads();
    f32x4 fa = z;
    #pragma unroll
    for (int i = 0; i < 16; ++i) {
      bf16x8 a = *(const bf16x8*)((const char*)h_lds + (PF ^ (i << 6)));
      fa = __builtin_amdgcn_mfma_f32_16x16x32_bf16(a, Wf[i], fa, 0, 0, 0);
    }
    int c = j0 + lc;
    if (c < OUTD) {
      #pragma unroll
      for (int q = 0; q < 4; ++q) {
        int b = row0 + w * 16 + kg * 4 + q;
        out[((long)b * 64 + 63) * OUTD + c] = fa[q] + fcb;
      }
    }
  }
}

extern "C" void kernel_launch(void* const* d_in, const int* in_sizes, int n_in,
                              void* d_out, int out_size, void* d_ws, size_t ws_size,
                              hipStream_t stream) {
  (void)in_sizes; (void)n_in; (void)out_size; (void)ws_size;
  const float* inp   = (const float*)d_in[0];
  const int*   labels= (const int*)d_in[1];
  const float* W_ih  = (const float*)d_in[3];
  const float* W_hh  = (const float*)d_in[4];
  const float* b_ih  = (const float*)d_in[5];
  const float* b_hh  = (const float*)d_in[6];
  const float* W_fc  = (const float*)d_in[7];
  const float* b_fc  = (const float*)d_in[8];
  const float* W_inh = (const float*)d_in[9];
  const float* b_inh = (const float*)d_in[10];
  const float* W_inc = (const float*)d_in[11];
  const float* b_inc = (const float*)d_in[12];

  // workspace layout (total ~8.65 MB)
  char* ws = (char*)d_ws;
  unsigned short* Weff = (unsigned short*)(ws + 0);          // 2,097,152 B (bf16 2048x512)
  float* bias_eff      = (float*)(ws + 2097152);             //     8,192 B
  unsigned short* hbuf = (unsigned short*)(ws + 2105344);    // 1,048,576 B (2 x 512 x 512 bf16)
  float* c0            = (float*)(ws + 3153920);             // 1,048,576 B
  float* corr0         = (float*)(ws + 4202496);             // 4,194,304 B
  float* d0            = (float*)(ws + 8396800);             //   135,168 B
  unsigned int* flags  = (unsigned int*)(ws + 8531968);      //    32,768 B (step flags + xmap + dec)
  unsigned short* Wfc16= (unsigned short*)(ws + 8564736);    //    67,584 B (bf16 66x512)
  unsigned int* flagsL = (unsigned int*)(ws + 8632320);      //    16,384 B (XCD-local flag channel)

  k_initA<<<512, 256, 0, stream>>>(W_hh, W_ih, W_fc, b_ih, b_hh, b_fc,
                                   inp, W_inh, b_inh, W_inc, b_inc,
                                   Weff, bias_eff, hbuf, c0, Wfc16, flags, flagsL);
  k_init2a<<<512, 128, 0, stream>>>(inp, hbuf, W_fc, b_fc, d0);
  k_init2b<<<128, 256, 0, stream>>>(d0, W_ih, corr0);

  k_main<<<256, 256, 0, stream>>>(Weff, bias_eff, hbuf, c0, corr0, W_ih, labels,
                                  Wfc16, b_fc, (float*)d_out, flags, flagsL);
}

// Round 13
// 502.558 us; speedup vs baseline: 33.6097x; 33.6097x over previous
//
#include <hip/hip_runtime.h>

#define OUTD 66
#define INW  78
#define FH   2048
#define LEN  64

typedef short bf16x8 __attribute__((ext_vector_type(8)));
typedef float f32x4  __attribute__((ext_vector_type(4)));

__device__ __forceinline__ float bf2f(unsigned short u) {
  union { unsigned int i; float f; } v; v.i = ((unsigned int)u) << 16; return v.f;
}
__device__ __forceinline__ unsigned short f2bf(float f) {
  union { float f; unsigned int i; } v; v.f = f;
  unsigned int u = v.i;
  return (unsigned short)((u + 0x7fffu + ((u >> 16) & 1u)) >> 16);
}
__device__ __forceinline__ float sigm(float x) { return 1.f / (1.f + __expf(-x)); }
__device__ __forceinline__ float tanh_f(float x) { return 2.f / (1.f + __expf(-2.f * x)) - 1.f; }

// ---- initA (all inputs FLOAT32):
//  blocks 0..255 : Weff(bf16) = W_hh + W_ihA·W_fc fold, bias_eff(f32), zero flags/flagsL
//  blocks 256..511: h0 -> hbuf[0] (bf16), c0 (f32); block 256 also converts W_fc -> Wfc16
__global__ __launch_bounds__(256) void k_initA(
    const float* __restrict__ W_hh, const float* __restrict__ W_ih,
    const float* __restrict__ W_fc, const float* __restrict__ b_ih,
    const float* __restrict__ b_hh, const float* __restrict__ b_fc,
    const float* __restrict__ inp, const float* __restrict__ W_inh,
    const float* __restrict__ b_inh, const float* __restrict__ W_inc,
    const float* __restrict__ b_inc,
    unsigned short* __restrict__ Weff, float* __restrict__ bias_eff,
    unsigned short* __restrict__ hbuf, float* __restrict__ c0,
    unsigned short* __restrict__ Wfc16, unsigned int* __restrict__ flags,
    unsigned int* __restrict__ flagsL)
{
  int tid = threadIdx.x, bid = blockIdx.x;
  if (bid < 256) {
    int nb = bid;
    int k = tid * 2;
    float acc[8][2];
    #pragma unroll
    for (int r = 0; r < 8; ++r) {
      int n = nb * 8 + r;
      acc[r][0] = W_hh[n * 512 + k];
      acc[r][1] = W_hh[n * 512 + k + 1];
    }
    for (int m = 0; m < OUTD; ++m) {
      float w0 = W_fc[m * 512 + k];
      float w1 = W_fc[m * 512 + k + 1];
      #pragma unroll
      for (int r = 0; r < 8; ++r) {
        float wih = W_ih[(nb * 8 + r) * INW + m];
        acc[r][0] += wih * w0;
        acc[r][1] += wih * w1;
      }
    }
    #pragma unroll
    for (int r = 0; r < 8; ++r) {
      int n = nb * 8 + r;
      unsigned int pack = (unsigned int)f2bf(acc[r][0]) | ((unsigned int)f2bf(acc[r][1]) << 16);
      *(unsigned int*)(Weff + n * 512 + k) = pack;
    }
    if (tid < 8) {
      int n = nb * 8 + tid;
      float a = b_ih[n] + b_hh[n];
      for (int m = 0; m < OUTD; ++m) a += b_fc[m] * W_ih[n * INW + m];
      bias_eff[n] = a;
    }
    if (nb == 0) {
      for (int i = tid; i < 512 * 16; i += 256) flags[i] = 0;
      for (int i = tid; i < 256 * 16; i += 256) flagsL[i] = 0;
    }
  } else {
    int nb = bid - 256;
    for (int r = 0; r < 2; ++r) {
      int b = nb * 2 + r;
      for (int half = 0; half < 2; ++half) {
        int c = tid + half * 256;
        float ha = b_inh[c], ca = b_inc[c];
        for (int m = 0; m < OUTD; ++m) {
          float f = inp[b * OUTD + m];
          ha += f * W_inh[c * OUTD + m];
          ca += f * W_inc[c * OUTD + m];
        }
        hbuf[b * 512 + c] = f2bf(ha);
        c0[b * 512 + c] = ca;
      }
    }
    if (nb == 0) {
      for (int i = tid; i < OUTD * 512; i += 256) Wfc16[i] = f2bf(W_fc[i]);
    }
  }
}

// ---- init2a: d0[b][m] = frame0 - (h0(bf16) @ W_fc^T + b_fc)
__global__ __launch_bounds__(128) void k_init2a(
    const float* __restrict__ inp, const unsigned short* __restrict__ hbuf,
    const float* __restrict__ W_fc, const float* __restrict__ b_fc,
    float* __restrict__ d0)
{
  int b = blockIdx.x, m = threadIdx.x;
  if (m >= OUTD) return;
  const unsigned short* hrow = hbuf + b * 512;
  const float* wrow = W_fc + m * 512;
  float acc = 0.f;
  for (int k = 0; k < 512; ++k) acc += bf2f(hrow[k]) * wrow[k];
  d0[b * OUTD + m] = inp[b * OUTD + m] - (acc + b_fc[m]);
}

// ---- init2b: corr0[b][n] = d0[b] @ W_ihA[n]^T
__global__ __launch_bounds__(256) void k_init2b(
    const float* __restrict__ d0, const float* __restrict__ W_ih,
    float* __restrict__ corr0)
{
  __shared__ float ds[4][OUTD];
  int tid = threadIdx.x, b0 = blockIdx.x * 4;
  for (int i = tid; i < 4 * OUTD; i += 256) ds[i / OUTD][i % OUTD] = d0[b0 * OUTD + i];
  __syncthreads();
  for (int n = tid; n < FH; n += 256) {
    float a0 = 0, a1 = 0, a2 = 0, a3 = 0;
    const float* wr = W_ih + n * INW;
    for (int m = 0; m < OUTD; ++m) {
      float w = wr[m];
      a0 += ds[0][m] * w; a1 += ds[1][m] * w; a2 += ds[2][m] * w; a3 += ds[3][m] * w;
    }
    corr0[(b0 + 0) * FH + n] = a0;
    corr0[(b0 + 1) * FH + n] = a1;
    corr0[(b0 + 2) * FH + n] = a2;
    corr0[(b0 + 3) * FH + n] = a3;
  }
}

// ---- main persistent LSTM kernel (r10 structure: LDS staging, wave0 poll).
// Fast-path consumer poll: plain `buffer_inv` (L1-ONLY invalidate, leaves local-L2
// fresh lines intact) + plain volatile load of the XCD-local flags -> local L2 hit.
// On success we SKIP the agent acquire fence (no sc1 L2 invalidate -> staging stays
// L2-resident). Bounded spins + permanent fallback to the r10-proven agent channel
// (worst case == r10, no hang). Producers dual-publish (local plain + agent sc1).
__global__ __launch_bounds__(256, 1) void k_main(
    const unsigned short* __restrict__ Weff, const float* __restrict__ bias_eff,
    unsigned short* __restrict__ hbuf, const float* __restrict__ c0,
    const float* __restrict__ corr0, const float* __restrict__ W_ih,
    const int* __restrict__ labels, const unsigned short* __restrict__ Wfc16,
    const float* __restrict__ b_fc, float* __restrict__ out,
    unsigned int* __restrict__ flags, unsigned int* __restrict__ flagsL)
{
  __shared__ __align__(16) unsigned short h_lds[64 * 512];  // 65536 B, XOR-swizzled 16B granules

  int tid = threadIdx.x, bid = blockIdx.x;
  int w = tid >> 6, lane = tid & 63;
  int lc = lane & 15, kg = lane >> 4;
  unsigned int* xmap = flags + 4096;          // [256] stride-16 XCD map
  unsigned int* decp = flags + 4088;          // decision word

  // ---- publish my XCC_ID (gfx950-verified: learn_hip m09)
  unsigned int xcd;
  asm volatile("s_getreg_b32 %0, hwreg(HW_REG_XCC_ID)" : "=s"(xcd));
  if (tid == 0)
    __hip_atomic_store(&xmap[bid * 16], xcd + 1u, __ATOMIC_RELAXED, __HIP_MEMORY_SCOPE_AGENT);

  // ---- leader (block 0, wave 0) verifies both candidate layouts, publishes decision
  if (bid == 0 && w == 0) {
    int okA = 1, okB = 1;
    #pragma unroll
    for (int i = 0; i < 4; ++i) {
      int b = lane + i * 64;
      unsigned int v, ra, rb;
      const unsigned int* xp = &xmap[b * 16];
      for (;;) { v = __hip_atomic_load(xp, __ATOMIC_RELAXED, __HIP_MEMORY_SCOPE_AGENT);
                 if (v) break; __builtin_amdgcn_s_sleep(1); }
      const unsigned int* pa = &xmap[(b & 7) * 16];
      for (;;) { ra = __hip_atomic_load(pa, __ATOMIC_RELAXED, __HIP_MEMORY_SCOPE_AGENT);
                 if (ra) break; __builtin_amdgcn_s_sleep(1); }
      const unsigned int* pb = &xmap[((b >> 5) << 5) * 16];
      for (;;) { rb = __hip_atomic_load(pb, __ATOMIC_RELAXED, __HIP_MEMORY_SCOPE_AGENT);
                 if (rb) break; __builtin_amdgcn_s_sleep(1); }
      okA &= (v == ra); okB &= (v == rb);
    }
    okA = __all(okA); okB = __all(okB);
    if (lane == 0) {
      unsigned int d = okA ? 1u : (okB ? 2u : 3u);
      __hip_atomic_store(decp, d, __ATOMIC_RELAXED, __HIP_MEMORY_SCOPE_AGENT);
    }
  }
  if (tid == 0) {
    unsigned int dd;
    for (;;) { dd = __hip_atomic_load(decp, __ATOMIC_RELAXED, __HIP_MEMORY_SCOPE_AGENT);
               if (dd) break; __builtin_amdgcn_s_sleep(1); }
    h_lds[0] = (unsigned short)dd;
  }
  __syncthreads();
  unsigned int dmode = h_lds[0];
  __syncthreads();

  int fast, mt, jt;
  if (dmode == 1u)      { fast = 1; mt = bid & 7;  jt = bid >> 3; }
  else if (dmode == 2u) { fast = 1; mt = bid >> 5; jt = bid & 31; }
  else                  { fast = 0; mt = bid & 7;  jt = bid >> 3; }

  int row0 = mt * 64, j0 = jt * 16;
  int hx0 = (w >> 1) * 8;
  int xloc = lc & 7;
  int G = lc >> 3;                       // 0: holds gates i,g ; 1: holds f,o
  int hcol = j0 + hx0 + xloc;            // global hidden col this lane activates
  int rw0 = (w & 1) * 32;                // wave-local row base

  // LDS swizzle precompute (addr_i = P ^ (i<<6))
  int sA = xloc;
  int tA16 = ((kg ^ sA) & 3) << 4;
  int ue64 = ((sA >> 2) & 1) << 6;
  int PA0 = (rw0 + lc) * 1024 + tA16 + ue64;
  int PA1 = PA0 + 16 * 1024;
  int PF  = (w * 16 + lc) * 1024 + tA16 + ue64;

  // ---- Weff B fragments (step-invariant)
  bf16x8 Bfrag[16][2];
  #pragma unroll
  for (int cg = 0; cg < 2; ++cg) {
    int n = (cg * 2 + G) * 512 + hcol;
    const unsigned short* p = Weff + n * 512 + kg * 8;
    #pragma unroll
    for (int i = 0; i < 16; ++i) Bfrag[i][cg] = *(const bf16x8*)(p + i * 32);
  }

  // ---- W_fc B fragments for fused fc (jt<5 covers out cols 0..79, guard <66)
  bf16x8 Wf[16];
  float fcb = 0.f;
  {
    int n = j0 + lc;
    if (jt < 5 && n < OUTD) {
      const unsigned short* p = Wfc16 + n * 512 + kg * 8;
      #pragma unroll
      for (int i = 0; i < 16; ++i) Wf[i] = *(const bf16x8*)(p + i * 32);
      fcb = b_fc[n];
    } else {
      bf16x8 z8 = {0, 0, 0, 0, 0, 0, 0, 0};
      #pragma unroll
      for (int i = 0; i < 16; ++i) Wf[i] = z8;
    }
  }

  // ---- activation constants
  int qsel = G * 2;
  float lt[4][4], creg[4];
  #pragma unroll
  for (int idx = 0; idx < 4; ++idx) {
    int rloc = rw0 + (idx >> 1) * 16 + kg * 4 + qsel + (idx & 1);
    int grow = row0 + rloc;
    int lab = labels[grow];
    #pragma unroll
    for (int gt = 0; gt < 4; ++gt) {
      int n = gt * 512 + hcol;
      lt[gt][idx] = bias_eff[n] + W_ih[n * INW + OUTD + lab];
    }
    creg[idx] = c0[grow * 512 + hcol];
  }

  const f32x4 z = {0.f, 0.f, 0.f, 0.f};
  unsigned int* myflag  = &flags[(mt * 32 + jt) * 16];
  unsigned int* myflagL = &flagsL[(mt * 32 + jt) * 16];
  const unsigned int* fpoll  = flags  + (mt * 32 + (lane & 31)) * 16;
  volatile const unsigned int* fpollL = flagsL + (mt * 32 + (lane & 31)) * 16;
  int useL = 1;   // adaptive: disabled permanently on first local-channel failure

  for (int s = 0; s < LEN; ++s) {
    // stage h_s (parity s&1) -> swizzled LDS
    const unsigned short* hsrc = hbuf + (s & 1) * 262144 + row0 * 512;
    #pragma unroll
    for (int i = 0; i < 16; ++i) {
      int chunk = tid + i * 256;
      int r = chunk >> 6, g = chunk & 63;
      int dst = r * 512 + ((g ^ (r & 7)) << 3);
      *(uint4*)(h_lds + dst) = *(const uint4*)(hsrc + r * 512 + g * 8);
    }
    __syncthreads();

    // gates = h_s @ Weff
    f32x4 acc00 = z, acc01 = z, acc10 = z, acc11 = z;
    #pragma unroll
    for (int i = 0; i < 16; ++i) {
      bf16x8 a0 = *(const bf16x8*)((const char*)h_lds + (PA0 ^ (i << 6)));
      bf16x8 a1 = *(const bf16x8*)((const char*)h_lds + (PA1 ^ (i << 6)));
      acc00 = __builtin_amdgcn_mfma_f32_16x16x32_bf16(a0, Bfrag[i][0], acc00, 0, 0, 0);
      acc10 = __builtin_amdgcn_mfma_f32_16x16x32_bf16(a1, Bfrag[i][0], acc10, 0, 0, 0);
      acc01 = __builtin_amdgcn_mfma_f32_16x16x32_bf16(a0, Bfrag[i][1], acc01, 0, 0, 0);
      acc11 = __builtin_amdgcn_mfma_f32_16x16x32_bf16(a1, Bfrag[i][1], acc11, 0, 0, 0);
    }

    // exchange missing gates with partner lane (lane^8)
    f32x4 sh00, sh01, sh10, sh11;
    #pragma unroll
    for (int j = 0; j < 4; ++j) {
      sh00[j] = __shfl_xor(acc00[j], 8);
      sh01[j] = __shfl_xor(acc01[j], 8);
      sh10[j] = __shfl_xor(acc10[j], 8);
      sh11[j] = __shfl_xor(acc11[j], 8);
    }

    // activation
    unsigned short hval[4];
    #pragma unroll
    for (int idx = 0; idx < 4; ++idx) {
      int jj = idx & 1, hh = idx >> 1;
      int qo = qsel + jj;
      float xi, xf, xg, xo;
      if (hh == 0) {
        xi = (G ? sh00[qo] : acc00[qo]);
        xf = (G ? acc00[qo] : sh00[qo]);
        xg = (G ? sh01[qo] : acc01[qo]);
        xo = (G ? acc01[qo] : sh01[qo]);
      } else {
        xi = (G ? sh10[qo] : acc10[qo]);
        xf = (G ? acc10[qo] : sh10[qo]);
        xg = (G ? sh11[qo] : acc11[qo]);
        xo = (G ? acc11[qo] : sh11[qo]);
      }
      xi += lt[0][idx]; xf += lt[1][idx]; xg += lt[2][idx]; xo += lt[3][idx];
      if (s == 0) {
        int rloc = rw0 + hh * 16 + kg * 4 + qo;
        const float* cr = corr0 + (long)(row0 + rloc) * FH + hcol;
        xi += cr[0]; xf += cr[512]; xg += cr[1024]; xo += cr[1536];
      }
      float cn = sigm(xf) * creg[idx] + sigm(xi) * tanh_f(xg);
      creg[idx] = cn;
      hval[idx] = f2bf(sigm(xo) * tanh_f(cn));
    }

    // ---- store h_{s+1} (opposite parity); pack lane pairs into u32.
    {
      unsigned int* hdst32 = (unsigned int*)(hbuf + ((s + 1) & 1) * 262144);
      int ce = (hcol & ~1) >> 1;
      int odd = xloc & 1;
      unsigned int pk[2]; int ro[2]; int np = 0;
      #pragma unroll
      for (int idx = 0; idx < 4; ++idx) {
        unsigned int mine = hval[idx];
        unsigned int part = (unsigned int)__shfl_xor((int)mine, 1);
        unsigned int p = odd ? (part | (mine << 16)) : (mine | (part << 16));
        if ((idx >> 1) == odd) {
          int rloc = rw0 + (idx >> 1) * 16 + kg * 4 + qsel + (idx & 1);
          pk[np] = p; ro[np] = (row0 + rloc) * 256 + ce; ++np;
        }
      }
      if (fast) {
        hdst32[ro[0]] = pk[0];
        hdst32[ro[1]] = pk[1];
      } else {
        __hip_atomic_store(&hdst32[ro[0]], pk[0], __ATOMIC_RELAXED, __HIP_MEMORY_SCOPE_AGENT);
        __hip_atomic_store(&hdst32[ro[1]], pk[1], __ATOMIC_RELAXED, __HIP_MEMORY_SCOPE_AGENT);
      }
    }

    // ---- producer flags: drain all h stores, then tid0 dual-publishes step.
    __builtin_amdgcn_s_waitcnt(0);
    __syncthreads();
    if (tid == 0) {
      if (fast) {
        *(volatile unsigned int*)myflagL = (unsigned int)(s + 1);  // local L2 channel
      }
      __hip_atomic_store(myflag, (unsigned int)(s + 1),            // L3 channel (always)
                         __ATOMIC_RELAXED, __HIP_MEMORY_SCOPE_AGENT);
    }

    // fused fc in the wait window: out[:, s-1, :] = h_s @ W_fc^T + b_fc
    if (jt < 5 && s >= 1) {
      f32x4 fa = z;
      #pragma unroll
      for (int i = 0; i < 16; ++i) {
        bf16x8 a = *(const bf16x8*)((const char*)h_lds + (PF ^ (i << 6)));
        fa = __builtin_amdgcn_mfma_f32_16x16x32_bf16(a, Wf[i], fa, 0, 0, 0);
      }
      int c = j0 + lc;
      if (c < OUTD) {
        #pragma unroll
        for (int q = 0; q < 4; ++q) {
          int b = row0 + w * 16 + kg * 4 + q;
          out[((long)b * 64 + (s - 1)) * OUTD + c] = fa[q] + fcb;
        }
      }
    }

    // ---- consumer wait (wave0): L1-only inv + plain load (local L2 hit),
    //      bounded; on failure fall back permanently to agent channel.
    if (w == 0) {
      int done = 0;
      if (fast && useL) {
        for (int t = 0; t < 512; ++t) {
          asm volatile("buffer_inv\n\ts_waitcnt vmcnt(0)" ::: "memory");
          unsigned int v = *fpollL;
          if (__all((int)(v >= (unsigned int)(s + 1)))) { done = 1; break; }
        }
        if (!done) useL = 0;
      }
      if (!done) {
        for (;;) {
          unsigned int v = __hip_atomic_load(fpoll, __ATOMIC_RELAXED, __HIP_MEMORY_SCOPE_AGENT);
          if (__all((int)(v >= (unsigned int)(s + 1)))) break;
          __builtin_amdgcn_s_sleep(1);
        }
        __builtin_amdgcn_fence(__ATOMIC_ACQUIRE, "agent");  // slow path: full inv
      }
      // fast-path success: L1 was invalidated right before the winning load; local
      // L2 holds the fresh h slab (producers drained before publishing) -> no fence.
    }
    __syncthreads();
  }

  // epilogue: out[:, 63, :] = h_64 @ W_fc^T + b_fc   (h_64 at parity 0)
  if (jt < 5) {
    const unsigned short* hsrc = hbuf + row0 * 512;
    #pragma unroll
    for (int i = 0; i < 16; ++i) {
      int chunk = tid + i * 256;
      int r = chunk >> 6, g = chunk & 63;
      int dst = r * 512 + ((g ^ (r & 7)) << 3);
      *(uint4*)(h_lds + dst) = *(const uint4*)(hsrc + r * 512 + g * 8);
    }
    __syncthreads();
    f32x4 fa = z;
    #pragma unroll
    for (int i = 0; i < 16; ++i) {
      bf16x8 a = *(const bf16x8*)((const char*)h_lds + (PF ^ (i << 6)));
      fa = __builtin_amdgcn_mfma_f32_16x16x32_bf16(a, Wf[i], fa, 0, 0, 0);
    }
    int c = j0 + lc;
    if (c < OUTD) {
      #pragma unroll
      for (int q = 0; q < 4; ++q) {
        int b = row0 + w * 16 + kg * 4 + q;
        out[((long)b * 64 + 63) * OUTD + c] = fa[q] + fcb;
      }
    }
  }
}

extern "C" void kernel_launch(void* const* d_in, const int* in_sizes, int n_in,
                              void* d_out, int out_size, void* d_ws, size_t ws_size,
                              hipStream_t stream) {
  (void)in_sizes; (void)n_in; (void)out_size; (void)ws_size;
  const float* inp   = (const float*)d_in[0];
  const int*   labels= (const int*)d_in[1];
  const float* W_ih  = (const float*)d_in[3];
  const float* W_hh  = (const float*)d_in[4];
  const float* b_ih  = (const float*)d_in[5];
  const float* b_hh  = (const float*)d_in[6];
  const float* W_fc  = (const float*)d_in[7];
  const float* b_fc  = (const float*)d_in[8];
  const float* W_inh = (const float*)d_in[9];
  const float* b_inh = (const float*)d_in[10];
  const float* W_inc = (const float*)d_in[11];
  const float* b_inc = (const float*)d_in[12];

  // workspace layout (total ~8.65 MB)
  char* ws = (char*)d_ws;
  unsigned short* Weff = (unsigned short*)(ws + 0);          // 2,097,152 B (bf16 2048x512)
  float* bias_eff      = (float*)(ws + 2097152);             //     8,192 B
  unsigned short* hbuf = (unsigned short*)(ws + 2105344);    // 1,048,576 B (2 x 512 x 512 bf16)
  float* c0            = (float*)(ws + 3153920);             // 1,048,576 B
  float* corr0         = (float*)(ws + 4202496);             // 4,194,304 B
  float* d0            = (float*)(ws + 8396800);             //   135,168 B
  unsigned int* flags  = (unsigned int*)(ws + 8531968);      //    32,768 B (step flags + xmap + dec)
  unsigned short* Wfc16= (unsigned short*)(ws + 8564736);    //    67,584 B (bf16 66x512)
  unsigned int* flagsL = (unsigned int*)(ws + 8632320);      //    16,384 B (XCD-local flag channel)

  k_initA<<<512, 256, 0, stream>>>(W_hh, W_ih, W_fc, b_ih, b_hh, b_fc,
                                   inp, W_inh, b_inh, W_inc, b_inc,
                                   Weff, bias_eff, hbuf, c0, Wfc16, flags, flagsL);
  k_init2a<<<512, 128, 0, stream>>>(inp, hbuf, W_fc, b_fc, d0);
  k_init2b<<<128, 256, 0, stream>>>(d0, W_ih, corr0);

  k_main<<<256, 256, 0, stream>>>(Weff, bias_eff, hbuf, c0, corr0, W_ih, labels,
                                  Wfc16, b_fc, (float*)d_out, flags, flagsL);
}